// Round 3
// baseline (520.472 us; speedup 1.0000x reference)
//
#include <hip/hip_runtime.h>
#include <cstdint>
#include <cstddef>

// ---------------------------------------------------------------------------
// GCN: 5 layers, out = Â (x W) + b per layer, SiLU on layers 0-3.
// Â = D^-1/2 (A + I) D^-1/2 built from edge_index with self-loops.
// Strategy:
//  - aggregate in the LOWEST-dim space (linearity): layer 0 aggregates the
//    3-dim input; layer 4's 128->3 matmul is fused into layer 3's GEMM
//    epilogue (PROJ) so layer 4 aggregates 3-dim.
//  - CSR build via LDS-binned multisplit (no 17x partial-line write
//    amplification): edges pack into 4B (src,dst < 2^16).
// ---------------------------------------------------------------------------

#define NB_SPLIT 256          // workgroups in prep/split passes
#define BUCKET_SHIFT 7        // 128 nodes per bucket

static __device__ __forceinline__ float silu_f(float x) {
  return x / (1.0f + __expf(-x));
}

// Detect whether edge_index is stored as int64 (odd int32 words all zero) or
// int32. flag = 1 -> int64 layout, 0 -> int32 layout.
__global__ void k_detect(const int* __restrict__ e32, int* __restrict__ flag) {
  __shared__ int any_nonzero;
  if (threadIdx.x == 0) any_nonzero = 0;
  __syncthreads();
  int v = e32[threadIdx.x * 2 + 1];
  if (v != 0) any_nonzero = 1;
  __syncthreads();
  if (threadIdx.x == 0) *flag = (any_nonzero ? 0 : 1);
}

// Pass A: pack edges to 4B records, per-node degree count (global atomics),
// per-(bucket, wg) histogram for the multisplit.
__global__ __launch_bounds__(256) void k_prep(
    const int* __restrict__ e32, const int* __restrict__ flag,
    int* __restrict__ epack, int* __restrict__ cnt, int* __restrict__ cnt2,
    int E, int nbucket, int chunk) {
  __shared__ int hist[512];
  const int w = blockIdx.x, t = threadIdx.x;
  for (int b = t; b < nbucket; b += 256) hist[b] = 0;
  __syncthreads();
  const int f = *flag;
  const int i0 = w * chunk;
  const int i1 = min(E, i0 + chunk);
  for (int i = i0 + t; i < i1; i += 256) {
    int s, d;
    if (f) { s = e32[2 * i]; d = e32[2 * E + 2 * i]; }
    else   { s = e32[i];     d = e32[E + i]; }
    epack[i] = s | (d << 16);            // requires N <= 65536 (N = 50000)
    atomicAdd(&cnt[d], 1);
    atomicAdd(&hist[d >> BUCKET_SHIFT], 1);
  }
  __syncthreads();
  for (int b = t; b < nbucket; b += 256) cnt2[b * NB_SPLIT + w] = hist[b];
}

// Hierarchical exclusive scan, stage 1: 1024 elems/block (4/thread).
// Optionally emits dis[i] = 1/sqrt(v_i + 1) (self-loop included).
__global__ void k_scan1(const int* __restrict__ cnt, int* __restrict__ outp,
                        int* __restrict__ bsum, float* __restrict__ dis, int n) {
  __shared__ int wsum[4];
  const int t = threadIdx.x;
  const int base = blockIdx.x * 1024 + t * 4;
  int v0 = 0, v1 = 0, v2 = 0, v3 = 0;
  if (base + 0 < n) v0 = cnt[base + 0];
  if (base + 1 < n) v1 = cnt[base + 1];
  if (base + 2 < n) v2 = cnt[base + 2];
  if (base + 3 < n) v3 = cnt[base + 3];
  if (dis) {
    if (base + 0 < n) dis[base + 0] = 1.0f / sqrtf((float)(v0 + 1));
    if (base + 1 < n) dis[base + 1] = 1.0f / sqrtf((float)(v1 + 1));
    if (base + 2 < n) dis[base + 2] = 1.0f / sqrtf((float)(v2 + 1));
    if (base + 3 < n) dis[base + 3] = 1.0f / sqrtf((float)(v3 + 1));
  }
  const int s = v0 + v1 + v2 + v3;
  int sc = s;
  const int lane = t & 63;
  #pragma unroll
  for (int o = 1; o < 64; o <<= 1) {
    int u = __shfl_up(sc, o);
    if (lane >= o) sc += u;
  }
  const int wid = t >> 6;
  if (lane == 63) wsum[wid] = sc;
  __syncthreads();
  int wbase = 0;
  for (int w = 0; w < wid; ++w) wbase += wsum[w];
  const int ex = wbase + sc - s;  // exclusive prefix of this thread's chunk
  if (base + 0 < n) outp[base + 0] = ex;
  if (base + 1 < n) outp[base + 1] = ex + v0;
  if (base + 2 < n) outp[base + 2] = ex + v0 + v1;
  if (base + 3 < n) outp[base + 3] = ex + v0 + v1 + v2;
  if (t == 0) bsum[blockIdx.x] = wsum[0] + wsum[1] + wsum[2] + wsum[3];
}

// Stage 2: serial exclusive scan of block sums (small) + write total.
__global__ void k_scan2(int* __restrict__ bsum, int nblk, int* __restrict__ total_out) {
  if (threadIdx.x == 0 && blockIdx.x == 0) {
    int acc = 0;
    for (int i = 0; i < nblk; ++i) { int v = bsum[i]; bsum[i] = acc; acc += v; }
    *total_out = acc;
  }
}

// Stage 3 (rowp-specific): add block offsets; also xs3 = pos * dis[row].
__global__ void k_scan3(int* __restrict__ rowp, const int* __restrict__ bsum,
                        const float* __restrict__ pos, const float* __restrict__ dis,
                        float* __restrict__ xs3, int n) {
  int i = blockIdx.x * blockDim.x + threadIdx.x;
  if (i < n) {
    rowp[i] += bsum[i >> 10];
    float d = dis[i];
    xs3[3 * i + 0] = pos[3 * i + 0] * d;
    xs3[3 * i + 1] = pos[3 * i + 1] * d;
    xs3[3 * i + 2] = pos[3 * i + 2] * d;
  }
}

// Generic stage 3: add block offsets only (for the off2 scan).
__global__ void k_scanadd(int* __restrict__ arr, const int* __restrict__ bsum, int n) {
  int i = blockIdx.x * blockDim.x + threadIdx.x;
  if (i < n) arr[i] += bsum[i >> 10];
}

// Pass B: scatter packed edges into bucket-grouped tmp; each (wg,bucket) owns
// a private contiguous sub-region -> L2 merges the 4B writes into full lines.
__global__ __launch_bounds__(256) void k_split(
    const int* __restrict__ epack, const int* __restrict__ off2,
    int* __restrict__ tmp, int E, int nbucket, int chunk) {
  __shared__ int cur[512];
  const int w = blockIdx.x, t = threadIdx.x;
  for (int b = t; b < nbucket; b += 256) cur[b] = off2[b * NB_SPLIT + w];
  __syncthreads();
  const int i0 = w * chunk;
  const int i1 = min(E, i0 + chunk);
  for (int i = i0 + t; i < i1; i += 256) {
    int p = epack[i];
    int b = (int)(((unsigned)p) >> (16 + BUCKET_SHIFT));
    int pos = atomicAdd(&cur[b], 1);
    tmp[pos] = p;
  }
}

// Pass C: one wg per bucket; per-node LDS cursors place edges into col.
// All writes land in a wg-private ~10KB window -> L2-absorbed.
__global__ __launch_bounds__(256) void k_csr(
    const int* __restrict__ tmp, const int* __restrict__ off2,
    const int* __restrict__ rowp, int* __restrict__ col,
    int E, int nbucket, int N) {
  __shared__ int cur[1 << BUCKET_SHIFT];
  const int b = blockIdx.x, t = threadIdx.x;
  const int nb0 = b << BUCKET_SHIFT;
  const int nn = min(1 << BUCKET_SHIFT, N - nb0);
  if (t < nn) cur[t] = rowp[nb0 + t];
  __syncthreads();
  const int s0 = off2[b * NB_SPLIT];
  const int s1 = (b + 1 < nbucket) ? off2[(b + 1) * NB_SPLIT] : E;
  for (int i = s0 + t; i < s1; i += 256) {
    unsigned p = (unsigned)tmp[i];
    int j = (int)((p >> 16) & ((1u << BUCKET_SHIFT) - 1));
    int pos = atomicAdd(&cur[j], 1);
    col[pos] = (int)(p & 0xffffu);
  }
}

// 3-dim aggregation: out3[i] = bias + dis[i] * (sum_{e in in(i)} in3[src_e] + in3[i])
// in3 must already be dis-prescaled. bias nullable.
__global__ void k_agg3(const float* __restrict__ in3, float* __restrict__ out3,
                       const int* __restrict__ rowp, const int* __restrict__ col,
                       const float* __restrict__ dis, const float* __restrict__ bias,
                       int n) {
  int i = blockIdx.x * blockDim.x + threadIdx.x;
  if (i >= n) return;
  float a0 = in3[i * 3 + 0], a1 = in3[i * 3 + 1], a2 = in3[i * 3 + 2];
  const int e0 = rowp[i], e1 = rowp[i + 1];
  for (int e = e0; e < e1; ++e) {
    int s = col[e];
    a0 += in3[s * 3 + 0];
    a1 += in3[s * 3 + 1];
    a2 += in3[s * 3 + 2];
  }
  const float d = dis[i];
  a0 *= d; a1 *= d; a2 *= d;
  if (bias) { a0 += bias[0]; a1 += bias[1]; a2 += bias[2]; }
  out3[i * 3 + 0] = a0;
  out3[i * 3 + 1] = a1;
  out3[i * 3 + 2] = a2;
}

// Layer 0 matmul: xs = silu(y3 @ W0 + b0) * dis.  Thread = (node, 4 cols).
__global__ void k_mm0(const float* __restrict__ y3, const float* __restrict__ W0,
                      const float* __restrict__ b0, const float* __restrict__ dis,
                      float* __restrict__ out, int n) {
  int gid = blockIdx.x * blockDim.x + threadIdx.x;
  int node = gid >> 5;
  int c = (gid & 31) << 2;
  if (node >= n) return;
  float v0 = y3[node * 3 + 0], v1 = y3[node * 3 + 1], v2 = y3[node * 3 + 2];
  float4 a  = *reinterpret_cast<const float4*>(b0 + c);
  float4 w0 = *reinterpret_cast<const float4*>(W0 + 0 * 128 + c);
  float4 w1 = *reinterpret_cast<const float4*>(W0 + 1 * 128 + c);
  float4 w2 = *reinterpret_cast<const float4*>(W0 + 2 * 128 + c);
  a.x += v0 * w0.x + v1 * w1.x + v2 * w2.x;
  a.y += v0 * w0.y + v1 * w1.y + v2 * w2.y;
  a.z += v0 * w0.z + v1 * w1.z + v2 * w2.z;
  a.w += v0 * w0.w + v1 * w1.w + v2 * w2.w;
  const float d = dis[node];
  a.x = silu_f(a.x) * d; a.y = silu_f(a.y) * d;
  a.z = silu_f(a.z) * d; a.w = silu_f(a.w) * d;
  *reinterpret_cast<float4*>(out + (size_t)node * 128 + c) = a;
}

// 128-dim aggregation: wave per node, lane holds 2 floats (float2).
// y[i] = dis[i] * (sum_{e in in(i)} xs[src_e] + xs[i]); 4-deep load pipelining.
__global__ void k_agg128(const float* __restrict__ xs, float* __restrict__ y,
                         const int* __restrict__ rowp, const int* __restrict__ col,
                         const float* __restrict__ dis, int n) {
  const int lane = threadIdx.x & 63;
  const int node = blockIdx.x * 4 + (threadIdx.x >> 6);
  if (node >= n) return;
  const float* __restrict__ xc = xs + lane * 2;
  const int e0 = rowp[node], e1 = rowp[node + 1];
  float2 acc0 = *reinterpret_cast<const float2*>(xc + (size_t)node * 128);  // self
  float2 acc1 = make_float2(0.f, 0.f);
  int e = e0;
  for (; e + 4 <= e1; e += 4) {
    int s0 = col[e], s1 = col[e + 1], s2 = col[e + 2], s3 = col[e + 3];
    float2 v0 = *reinterpret_cast<const float2*>(xc + (size_t)s0 * 128);
    float2 v1 = *reinterpret_cast<const float2*>(xc + (size_t)s1 * 128);
    float2 v2 = *reinterpret_cast<const float2*>(xc + (size_t)s2 * 128);
    float2 v3 = *reinterpret_cast<const float2*>(xc + (size_t)s3 * 128);
    acc0.x += v0.x + v1.x; acc0.y += v0.y + v1.y;
    acc1.x += v2.x + v3.x; acc1.y += v2.y + v3.y;
  }
  for (; e < e1; ++e) {
    int s = col[e];
    float2 v = *reinterpret_cast<const float2*>(xc + (size_t)s * 128);
    acc0.x += v.x; acc0.y += v.y;
  }
  const float d = dis[node];
  float2 r;
  r.x = (acc0.x + acc1.x) * d;
  r.y = (acc0.y + acc1.y) * d;
  *reinterpret_cast<float2*>(y + (size_t)node * 128 + lane * 2) = r;
}

// Middle matmul: h = silu(x @ W + b) * dis   [N x 128]x[128 x 128]
// Tile 32 rows x 128 cols, 256 threads, 4x4 register blocking, W staged in LDS,
// float4-over-k inner loop (LDS b128 only).
// PROJ=0: store h (128-dim). PROJ=1: also project h @ W4 (128->3) and store
// ONLY the 3-dim result (layer-3 + layer-4-matmul fusion).
template <int PROJ>
__global__ __launch_bounds__(256) void k_mm_mid(
    const float* __restrict__ x, const float* __restrict__ W,
    const float* __restrict__ bias, const float* __restrict__ dis,
    float* __restrict__ out, const float* __restrict__ W4, int n) {
  __shared__ float xs[32][128];
  __shared__ float ws[32][128];
  const int t = threadIdx.x;
  const int row0 = blockIdx.x * 32;

  // stage x tile (32 x 128), zero-padded past n
  {
    int i = t;
    #pragma unroll
    for (int it = 0; it < 4; ++it, i += 256) {
      int r = i >> 5;
      int c4 = (i & 31) << 2;
      float4 v = make_float4(0.f, 0.f, 0.f, 0.f);
      int row = row0 + r;
      if (row < n) v = *reinterpret_cast<const float4*>(x + (size_t)row * 128 + c4);
      *reinterpret_cast<float4*>(&xs[r][c4]) = v;
    }
  }

  const int tc = (t & 31) << 2;  // 4 cols
  const int tr = (t >> 5) << 2;  // 4 rows
  float4 acc[4];
  #pragma unroll
  for (int r = 0; r < 4; ++r) acc[r] = make_float4(0.f, 0.f, 0.f, 0.f);

  for (int kc = 0; kc < 128; kc += 32) {
    __syncthreads();
    // stage W[kc..kc+32)[0..128)
    {
      int i = t;
      #pragma unroll
      for (int it = 0; it < 4; ++it, i += 256) {
        int r = i >> 5;
        int c4 = (i & 31) << 2;
        *reinterpret_cast<float4*>(&ws[r][c4]) =
            *reinterpret_cast<const float4*>(W + (size_t)(kc + r) * 128 + c4);
      }
    }
    __syncthreads();
    #pragma unroll
    for (int kk = 0; kk < 32; kk += 4) {
      float4 w0 = *reinterpret_cast<const float4*>(&ws[kk + 0][tc]);
      float4 w1 = *reinterpret_cast<const float4*>(&ws[kk + 1][tc]);
      float4 w2 = *reinterpret_cast<const float4*>(&ws[kk + 2][tc]);
      float4 w3 = *reinterpret_cast<const float4*>(&ws[kk + 3][tc]);
      #pragma unroll
      for (int r = 0; r < 4; ++r) {
        float4 xr = *reinterpret_cast<const float4*>(&xs[tr + r][kc + kk]);
        acc[r].x += xr.x * w0.x + xr.y * w1.x + xr.z * w2.x + xr.w * w3.x;
        acc[r].y += xr.x * w0.y + xr.y * w1.y + xr.z * w2.y + xr.w * w3.y;
        acc[r].z += xr.x * w0.z + xr.y * w1.z + xr.z * w2.z + xr.w * w3.z;
        acc[r].w += xr.x * w0.w + xr.y * w1.w + xr.z * w2.w + xr.w * w3.w;
      }
    }
  }

  float4 bb = *reinterpret_cast<const float4*>(bias + tc);
  if (PROJ) {
    // Per-thread 4-col slice of W4 (128x3).
    float w4r[4][3];
    #pragma unroll
    for (int c = 0; c < 4; ++c) {
      w4r[c][0] = W4[(tc + c) * 3 + 0];
      w4r[c][1] = W4[(tc + c) * 3 + 1];
      w4r[c][2] = W4[(tc + c) * 3 + 2];
    }
    #pragma unroll
    for (int r = 0; r < 4; ++r) {
      int row = row0 + tr + r;
      float d = (row < n) ? dis[row] : 0.0f;
      float4 a = acc[r];
      a.x = silu_f(a.x + bb.x) * d;
      a.y = silu_f(a.y + bb.y) * d;
      a.z = silu_f(a.z + bb.z) * d;
      a.w = silu_f(a.w + bb.w) * d;
      float p0 = a.x * w4r[0][0] + a.y * w4r[1][0] + a.z * w4r[2][0] + a.w * w4r[3][0];
      float p1 = a.x * w4r[0][1] + a.y * w4r[1][1] + a.z * w4r[2][1] + a.w * w4r[3][1];
      float p2 = a.x * w4r[0][2] + a.y * w4r[1][2] + a.z * w4r[2][2] + a.w * w4r[3][2];
      // reduce across the 32 threads sharing this row (xor stays in-half)
      #pragma unroll
      for (int m = 16; m >= 1; m >>= 1) {
        p0 += __shfl_xor(p0, m);
        p1 += __shfl_xor(p1, m);
        p2 += __shfl_xor(p2, m);
      }
      if ((t & 31) == 0 && row < n) {
        out[row * 3 + 0] = p0;
        out[row * 3 + 1] = p1;
        out[row * 3 + 2] = p2;
      }
    }
  } else {
    #pragma unroll
    for (int r = 0; r < 4; ++r) {
      int row = row0 + tr + r;
      if (row < n) {
        float4 a = acc[r];
        float d = dis[row];
        a.x = silu_f(a.x + bb.x) * d;
        a.y = silu_f(a.y + bb.y) * d;
        a.z = silu_f(a.z + bb.z) * d;
        a.w = silu_f(a.w + bb.w) * d;
        *reinterpret_cast<float4*>(out + (size_t)row * 128 + tc) = a;
      }
    }
  }
}

extern "C" void kernel_launch(void* const* d_in, const int* in_sizes, int n_in,
                              void* d_out, int out_size, void* d_ws, size_t ws_size,
                              hipStream_t stream) {
  const float* pos = (const float*)d_in[0];
  const int* e32 = (const int*)d_in[1];
  const float* W[5] = {(const float*)d_in[2], (const float*)d_in[4], (const float*)d_in[6],
                       (const float*)d_in[8], (const float*)d_in[10]};
  const float* B[5] = {(const float*)d_in[3], (const float*)d_in[5], (const float*)d_in[7],
                       (const float*)d_in[9], (const float*)d_in[11]};
  float* out = (float*)d_out;

  const int N = in_sizes[0] / 3;
  const int E = in_sizes[1] / 2;
  const int NBUCKET = (N + (1 << BUCKET_SHIFT) - 1) >> BUCKET_SHIFT;  // 391
  const int M = NBUCKET * NB_SPLIT;                                    // off2 size
  const int chunk = (E + NB_SPLIT - 1) / NB_SPLIT;

  char* base = (char*)d_ws;
  size_t off = 0;
  auto alloc = [&](size_t bytes) -> void* {
    void* p = base + off;
    off += (bytes + 255) & ~(size_t)255;
    return p;
  };
  float* dis   = (float*)alloc((size_t)N * 4);
  int* cnt     = (int*)alloc((size_t)N * 4);
  int* rowp    = (int*)alloc((size_t)(N + 1) * 4);
  int* bsum    = (int*)alloc(64 * 4);
  int* bsum2   = (int*)alloc(128 * 4);
  int* flag    = (int*)alloc(256);            // [0]=layout flag, [1]=scratch total
  int* cnt2    = (int*)alloc((size_t)M * 4);
  int* off2    = (int*)alloc((size_t)M * 4);
  int* col     = (int*)alloc((size_t)E * 4);
  float* xs3   = (float*)alloc((size_t)N * 3 * 4);
  float* y3    = (float*)alloc((size_t)N * 3 * 4);
  float* bufA  = (float*)alloc((size_t)N * 128 * 4);
  float* bufB  = (float*)alloc((size_t)N * 128 * 4);
  // epack/tmp are only live during CSR build; alias the big activation buffers.
  int* epack = (int*)bufA;
  int* tmp   = (int*)bufB;

  const int nblk  = (N + 1023) / 1024;   // 49
  const int nblk2 = (M + 1023) / 1024;   // 98

  // --- CSR build ---
  hipMemsetAsync(cnt, 0, (size_t)N * 4, stream);
  k_detect<<<1, 256, 0, stream>>>(e32, flag);
  k_prep<<<NB_SPLIT, 256, 0, stream>>>(e32, flag, epack, cnt, cnt2, E, NBUCKET, chunk);
  // rowp = exclusive scan of cnt (+ dis, + xs3 prescale)
  k_scan1<<<nblk, 256, 0, stream>>>(cnt, rowp, bsum, dis, N);
  k_scan2<<<1, 64, 0, stream>>>(bsum, nblk, rowp + N);
  k_scan3<<<(N + 255) / 256, 256, 0, stream>>>(rowp, bsum, pos, dis, xs3, N);
  // off2 = exclusive scan of cnt2 (bucket-major)
  k_scan1<<<nblk2, 256, 0, stream>>>(cnt2, off2, bsum2, nullptr, M);
  k_scan2<<<1, 64, 0, stream>>>(bsum2, nblk2, flag + 1);
  k_scanadd<<<(M + 255) / 256, 256, 0, stream>>>(off2, bsum2, M);
  // bucket-split then per-bucket CSR finalize
  k_split<<<NB_SPLIT, 256, 0, stream>>>(epack, off2, tmp, E, NBUCKET, chunk);
  k_csr<<<NBUCKET, 256, 0, stream>>>(tmp, off2, rowp, col, E, NBUCKET, N);

  // --- layer 0: aggregate pos (3-dim) then 3->128 matmul + SiLU + dis ---
  k_agg3<<<(N + 255) / 256, 256, 0, stream>>>(xs3, y3, rowp, col, dis, nullptr, N);
  k_mm0<<<(N * 32 + 255) / 256, 256, 0, stream>>>(y3, W[0], B[0], dis, bufA, N);

  // --- layers 1..2: aggregate (128) then 128x128 matmul + SiLU + dis ---
  for (int l = 1; l <= 2; ++l) {
    k_agg128<<<(N + 3) / 4, 256, 0, stream>>>(bufA, bufB, rowp, col, dis, N);
    k_mm_mid<0><<<(N + 31) / 32, 256, 0, stream>>>(bufB, W[l], B[l], dis, bufA, nullptr, N);
  }

  // --- layer 3: aggregate, matmul fused with layer-4's 128->3 projection ---
  k_agg128<<<(N + 3) / 4, 256, 0, stream>>>(bufA, bufB, rowp, col, dis, N);
  k_mm_mid<1><<<(N + 31) / 32, 256, 0, stream>>>(bufB, W[3], B[3], dis, y3, W[4], N);

  // --- layer 4: 3-dim aggregate + bias ---
  k_agg3<<<(N + 255) / 256, 256, 0, stream>>>(y3, out, rowp, col, dis, B[4], N);

  (void)n_in; (void)out_size; (void)ws_size;
}

// Round 4
// 415.891 us; speedup vs baseline: 1.2515x; 1.2515x over previous
//
#include <hip/hip_runtime.h>
#include <cstdint>
#include <cstddef>

// ---------------------------------------------------------------------------
// GCN: 5 layers, out = Â (x W) + b per layer, SiLU on layers 0-3.
// Â = D^-1/2 (A + I) D^-1/2 built from edge_index with self-loops.
//  - aggregate in the LOWEST-dim space (linearity): layer 0 aggregates the
//    3-dim input; layer 4's 128->3 matmul is fused into layer 3's GEMM
//    epilogue (PROJ) so layer 4 aggregates 3-dim.
//  - CSR build via LDS-binned multisplit; per-node degrees/rowp/dis derived
//    inside k_csr from the bucket-sorted stream (no global cnt atomics).
//  - GEMM: W (64 KB) resident in LDS, barrier-free main loop, x broadcast
//    from global. (Round-3 lesson: per-kc barriers + 3 wg/CU = 25% VALU.)
// ---------------------------------------------------------------------------

#define NB_SPLIT 256          // workgroups in prep/split passes
#define BUCKET_SHIFT 7        // 128 nodes per bucket

static __device__ __forceinline__ float silu_f(float x) {
  return x / (1.0f + __expf(-x));
}

// Detect whether edge_index is stored as int64 (odd int32 words all zero) or
// int32. flag = 1 -> int64 layout, 0 -> int32 layout.
__global__ void k_detect(const int* __restrict__ e32, int* __restrict__ flag) {
  __shared__ int any_nonzero;
  if (threadIdx.x == 0) any_nonzero = 0;
  __syncthreads();
  int v = e32[threadIdx.x * 2 + 1];
  if (v != 0) any_nonzero = 1;
  __syncthreads();
  if (threadIdx.x == 0) *flag = (any_nonzero ? 0 : 1);
}

// Pass A: pack edges to 4B records + per-(bucket, wg) histogram.
__global__ __launch_bounds__(256) void k_prep(
    const int* __restrict__ e32, const int* __restrict__ flag,
    int* __restrict__ epack, int* __restrict__ cnt2,
    int E, int nbucket, int chunk) {
  __shared__ int hist[512];
  const int w = blockIdx.x, t = threadIdx.x;
  for (int b = t; b < nbucket; b += 256) hist[b] = 0;
  __syncthreads();
  const int f = *flag;
  const int i0 = w * chunk;
  const int i1 = min(E, i0 + chunk);
  for (int i = i0 + t; i < i1; i += 256) {
    int s, d;
    if (f) { s = e32[2 * i]; d = e32[2 * E + 2 * i]; }
    else   { s = e32[i];     d = e32[E + i]; }
    epack[i] = s | (d << 16);            // requires N <= 65536 (N = 50000)
    atomicAdd(&hist[d >> BUCKET_SHIFT], 1);
  }
  __syncthreads();
  for (int b = t; b < nbucket; b += 256) cnt2[b * NB_SPLIT + w] = hist[b];
}

// Hierarchical exclusive scan, stage 1: 1024 elems/block (4/thread).
__global__ void k_scan1(const int* __restrict__ cnt, int* __restrict__ outp,
                        int* __restrict__ bsum, int n) {
  __shared__ int wsum[4];
  const int t = threadIdx.x;
  const int base = blockIdx.x * 1024 + t * 4;
  int v0 = 0, v1 = 0, v2 = 0, v3 = 0;
  if (base + 0 < n) v0 = cnt[base + 0];
  if (base + 1 < n) v1 = cnt[base + 1];
  if (base + 2 < n) v2 = cnt[base + 2];
  if (base + 3 < n) v3 = cnt[base + 3];
  const int s = v0 + v1 + v2 + v3;
  int sc = s;
  const int lane = t & 63;
  #pragma unroll
  for (int o = 1; o < 64; o <<= 1) {
    int u = __shfl_up(sc, o);
    if (lane >= o) sc += u;
  }
  const int wid = t >> 6;
  if (lane == 63) wsum[wid] = sc;
  __syncthreads();
  int wbase = 0;
  for (int w = 0; w < wid; ++w) wbase += wsum[w];
  const int ex = wbase + sc - s;
  if (base + 0 < n) outp[base + 0] = ex;
  if (base + 1 < n) outp[base + 1] = ex + v0;
  if (base + 2 < n) outp[base + 2] = ex + v0 + v1;
  if (base + 3 < n) outp[base + 3] = ex + v0 + v1 + v2;
  if (t == 0) bsum[blockIdx.x] = wsum[0] + wsum[1] + wsum[2] + wsum[3];
}

// Stage 2: serial exclusive scan of block sums (small).
__global__ void k_scan2(int* __restrict__ bsum, int nblk) {
  if (threadIdx.x == 0 && blockIdx.x == 0) {
    int acc = 0;
    for (int i = 0; i < nblk; ++i) { int v = bsum[i]; bsum[i] = acc; acc += v; }
  }
}

// Stage 3: add block offsets.
__global__ void k_scanadd(int* __restrict__ arr, const int* __restrict__ bsum, int n) {
  int i = blockIdx.x * blockDim.x + threadIdx.x;
  if (i < n) arr[i] += bsum[i >> 10];
}

// Pass B: scatter packed edges into bucket-grouped tmp; each (wg,bucket) owns
// a private contiguous sub-region -> L2 merges the 4B writes into full lines.
__global__ __launch_bounds__(256) void k_split(
    const int* __restrict__ epack, const int* __restrict__ off2,
    int* __restrict__ tmp, int E, int nbucket, int chunk) {
  __shared__ int cur[512];
  const int w = blockIdx.x, t = threadIdx.x;
  for (int b = t; b < nbucket; b += 256) cur[b] = off2[b * NB_SPLIT + w];
  __syncthreads();
  const int i0 = w * chunk;
  const int i1 = min(E, i0 + chunk);
  for (int i = i0 + t; i < i1; i += 256) {
    int p = epack[i];
    int b = (int)(((unsigned)p) >> (16 + BUCKET_SHIFT));
    int pos = atomicAdd(&cur[b], 1);
    tmp[pos] = p;
  }
}

// Pass C: one wg per bucket. Counts per-node degree from the bucket's edge
// stream (LDS), scans it (128-wide), writes rowp + dis, then places edges.
__global__ __launch_bounds__(256) void k_csr(
    const int* __restrict__ tmp, const int* __restrict__ off2,
    int* __restrict__ rowp, float* __restrict__ dis, int* __restrict__ col,
    int E, int nbucket, int N) {
  __shared__ int lcnt[128];
  __shared__ int lcur[128];
  __shared__ int wtot;
  const int b = blockIdx.x, t = threadIdx.x;
  const int nb0 = b << BUCKET_SHIFT;
  const int nn = min(1 << BUCKET_SHIFT, N - nb0);
  if (t < 128) lcnt[t] = 0;
  __syncthreads();
  const int s0 = off2[b * NB_SPLIT];
  const int s1 = (b + 1 < nbucket) ? off2[(b + 1) * NB_SPLIT] : E;
  for (int i = s0 + t; i < s1; i += 256) {
    atomicAdd(&lcnt[((unsigned)tmp[i] >> 16) & 127u], 1);
  }
  __syncthreads();
  int v = 0, sc = 0;
  if (t < 128) {
    v = lcnt[t];
    sc = v;
    #pragma unroll
    for (int o = 1; o < 64; o <<= 1) {
      int u = __shfl_up(sc, o);
      if ((t & 63) >= o) sc += u;
    }
    if (t == 63) wtot = sc;          // wave-0 inclusive total
  }
  __syncthreads();
  if (t < 128) {
    int ex = s0 + ((t >= 64) ? wtot : 0) + sc - v;   // exclusive prefix
    lcur[t] = ex;
    if (t < nn) {
      rowp[nb0 + t] = ex;
      dis[nb0 + t] = rsqrtf((float)(v + 1));
    }
  }
  if (t == 0) rowp[nb0 + nn] = s1;   // bucket end (== next bucket's start)
  __syncthreads();
  for (int i = s0 + t; i < s1; i += 256) {
    unsigned p = (unsigned)tmp[i];
    int j = (int)((p >> 16) & ((1u << BUCKET_SHIFT) - 1));
    int pos = atomicAdd(&lcur[j], 1);
    col[pos] = (int)(p & 0xffffu);
  }
}

// 3-dim aggregation.
// PRESCALE=1: out3[i] = dis[i] * (sum_e in3[s]*dis[s] + in3[i]*dis[i])
// PRESCALE=0: out3[i] = bias + dis[i] * (sum_e in3[s] + in3[i])   (in3 pre-scaled)
template <int PRESCALE>
__global__ void k_agg3(const float* __restrict__ in3, float* __restrict__ out3,
                       const int* __restrict__ rowp, const int* __restrict__ col,
                       const float* __restrict__ dis, const float* __restrict__ bias,
                       int n) {
  int i = blockIdx.x * blockDim.x + threadIdx.x;
  if (i >= n) return;
  const float di = dis[i];
  float a0, a1, a2;
  if (PRESCALE) {
    a0 = in3[i * 3 + 0] * di; a1 = in3[i * 3 + 1] * di; a2 = in3[i * 3 + 2] * di;
  } else {
    a0 = in3[i * 3 + 0]; a1 = in3[i * 3 + 1]; a2 = in3[i * 3 + 2];
  }
  const int e0 = rowp[i], e1 = rowp[i + 1];
  for (int e = e0; e < e1; ++e) {
    int s = col[e];
    if (PRESCALE) {
      float ds_ = dis[s];
      a0 += in3[s * 3 + 0] * ds_;
      a1 += in3[s * 3 + 1] * ds_;
      a2 += in3[s * 3 + 2] * ds_;
    } else {
      a0 += in3[s * 3 + 0];
      a1 += in3[s * 3 + 1];
      a2 += in3[s * 3 + 2];
    }
  }
  a0 *= di; a1 *= di; a2 *= di;
  if (!PRESCALE && bias) { a0 += bias[0]; a1 += bias[1]; a2 += bias[2]; }
  out3[i * 3 + 0] = a0;
  out3[i * 3 + 1] = a1;
  out3[i * 3 + 2] = a2;
}

// Layer 0 matmul: xs = silu(y3 @ W0 + b0) * dis.  Thread = (node, 4 cols).
__global__ void k_mm0(const float* __restrict__ y3, const float* __restrict__ W0,
                      const float* __restrict__ b0, const float* __restrict__ dis,
                      float* __restrict__ out, int n) {
  int gid = blockIdx.x * blockDim.x + threadIdx.x;
  int node = gid >> 5;
  int c = (gid & 31) << 2;
  if (node >= n) return;
  float v0 = y3[node * 3 + 0], v1 = y3[node * 3 + 1], v2 = y3[node * 3 + 2];
  float4 a  = *reinterpret_cast<const float4*>(b0 + c);
  float4 w0 = *reinterpret_cast<const float4*>(W0 + 0 * 128 + c);
  float4 w1 = *reinterpret_cast<const float4*>(W0 + 1 * 128 + c);
  float4 w2 = *reinterpret_cast<const float4*>(W0 + 2 * 128 + c);
  a.x += v0 * w0.x + v1 * w1.x + v2 * w2.x;
  a.y += v0 * w0.y + v1 * w1.y + v2 * w2.y;
  a.z += v0 * w0.z + v1 * w1.z + v2 * w2.z;
  a.w += v0 * w0.w + v1 * w1.w + v2 * w2.w;
  const float d = dis[node];
  a.x = silu_f(a.x) * d; a.y = silu_f(a.y) * d;
  a.z = silu_f(a.z) * d; a.w = silu_f(a.w) * d;
  *reinterpret_cast<float4*>(out + (size_t)node * 128 + c) = a;
}

// 128-dim aggregation: wave per node, float4 per lane, 2 edges per wave
// instruction (half-wave per edge), unroll 4 -> 8 gathers in flight.
__global__ __launch_bounds__(256) void k_agg128(
    const float* __restrict__ xs, float* __restrict__ y,
    const int* __restrict__ rowp, const int* __restrict__ col,
    const float* __restrict__ dis, int n) {
  const int lane = threadIdx.x & 63;
  const int node = blockIdx.x * 4 + (threadIdx.x >> 6);
  if (node >= n) return;
  const int half = lane >> 5;
  const int c0 = (lane & 31) << 2;
  const float* __restrict__ xc = xs + c0;
  const int e0 = rowp[node], e1 = rowp[node + 1];
  float4 acc = make_float4(0.f, 0.f, 0.f, 0.f);
  if (!half) acc = *reinterpret_cast<const float4*>(xc + (size_t)node * 128);  // self
  int e = e0 + half;               // halves take alternating edges
  for (; e + 6 < e1; e += 8) {
    int s0 = col[e], s1 = col[e + 2], s2 = col[e + 4], s3 = col[e + 6];
    float4 v0 = *reinterpret_cast<const float4*>(xc + (size_t)s0 * 128);
    float4 v1 = *reinterpret_cast<const float4*>(xc + (size_t)s1 * 128);
    float4 v2 = *reinterpret_cast<const float4*>(xc + (size_t)s2 * 128);
    float4 v3 = *reinterpret_cast<const float4*>(xc + (size_t)s3 * 128);
    acc.x += v0.x + v1.x + v2.x + v3.x;
    acc.y += v0.y + v1.y + v2.y + v3.y;
    acc.z += v0.z + v1.z + v2.z + v3.z;
    acc.w += v0.w + v1.w + v2.w + v3.w;
  }
  for (; e < e1; e += 2) {
    int s = col[e];
    float4 v = *reinterpret_cast<const float4*>(xc + (size_t)s * 128);
    acc.x += v.x; acc.y += v.y; acc.z += v.z; acc.w += v.w;
  }
  acc.x += __shfl_xor(acc.x, 32);
  acc.y += __shfl_xor(acc.y, 32);
  acc.z += __shfl_xor(acc.z, 32);
  acc.w += __shfl_xor(acc.w, 32);
  if (!half) {
    const float d = dis[node];
    acc.x *= d; acc.y *= d; acc.z *= d; acc.w *= d;
    *reinterpret_cast<float4*>(y + (size_t)node * 128 + c0) = acc;
  }
}

// Middle matmul: h = silu(x @ W + b) * dis.  W (64 KB) resident in LDS, staged
// once; main loop has NO barriers. 512 threads, 64-row tile per wg, thread =
// 4 rows x 4 cols. x read from global (half-wave broadcast -> 16B coalesced).
// PROJ=1: also project h @ W4 (128->3) and store only the 3-dim result.
template <int PROJ>
__global__ __launch_bounds__(512) void k_mm_w(
    const float* __restrict__ x, const float* __restrict__ W,
    const float* __restrict__ bias, const float* __restrict__ dis,
    float* __restrict__ out, const float* __restrict__ W4, int n) {
  __shared__ float ws[128][128];
  const int t = threadIdx.x;
  #pragma unroll
  for (int it = 0; it < 8; ++it) {
    int i = t + it * 512;            // float4 index over 128x128
    *reinterpret_cast<float4*>(&ws[i >> 5][(i & 31) << 2]) =
        *reinterpret_cast<const float4*>(W + (size_t)i * 4);
  }
  __syncthreads();

  const int tc = (t & 31) << 2;      // 4 cols
  const int tr = (t >> 5) << 2;      // 4 rows within the 64-row tile
  const int row0 = blockIdx.x * 64;

  const float* xp[4];
  #pragma unroll
  for (int r = 0; r < 4; ++r) {
    int row = row0 + tr + r;
    xp[r] = x + (size_t)min(row, n - 1) * 128;   // clamped; results discarded
  }

  float4 acc[4];
  #pragma unroll
  for (int r = 0; r < 4; ++r) acc[r] = make_float4(0.f, 0.f, 0.f, 0.f);

  #pragma unroll 2
  for (int kk = 0; kk < 128; kk += 4) {
    float4 w0 = *reinterpret_cast<const float4*>(&ws[kk + 0][tc]);
    float4 w1 = *reinterpret_cast<const float4*>(&ws[kk + 1][tc]);
    float4 w2 = *reinterpret_cast<const float4*>(&ws[kk + 2][tc]);
    float4 w3 = *reinterpret_cast<const float4*>(&ws[kk + 3][tc]);
    #pragma unroll
    for (int r = 0; r < 4; ++r) {
      float4 xr = *reinterpret_cast<const float4*>(xp[r] + kk);
      acc[r].x += xr.x * w0.x + xr.y * w1.x + xr.z * w2.x + xr.w * w3.x;
      acc[r].y += xr.x * w0.y + xr.y * w1.y + xr.z * w2.y + xr.w * w3.y;
      acc[r].z += xr.x * w0.z + xr.y * w1.z + xr.z * w2.z + xr.w * w3.z;
      acc[r].w += xr.x * w0.w + xr.y * w1.w + xr.z * w2.w + xr.w * w3.w;
    }
  }

  float4 bb = *reinterpret_cast<const float4*>(bias + tc);
  if (PROJ) {
    float w4r[4][3];
    #pragma unroll
    for (int c = 0; c < 4; ++c) {
      w4r[c][0] = W4[(tc + c) * 3 + 0];
      w4r[c][1] = W4[(tc + c) * 3 + 1];
      w4r[c][2] = W4[(tc + c) * 3 + 2];
    }
    #pragma unroll
    for (int r = 0; r < 4; ++r) {
      int row = row0 + tr + r;
      float d = (row < n) ? dis[row] : 0.0f;
      float4 a = acc[r];
      a.x = silu_f(a.x + bb.x) * d;
      a.y = silu_f(a.y + bb.y) * d;
      a.z = silu_f(a.z + bb.z) * d;
      a.w = silu_f(a.w + bb.w) * d;
      float p0 = a.x * w4r[0][0] + a.y * w4r[1][0] + a.z * w4r[2][0] + a.w * w4r[3][0];
      float p1 = a.x * w4r[0][1] + a.y * w4r[1][1] + a.z * w4r[2][1] + a.w * w4r[3][1];
      float p2 = a.x * w4r[0][2] + a.y * w4r[1][2] + a.z * w4r[2][2] + a.w * w4r[3][2];
      #pragma unroll
      for (int m = 16; m >= 1; m >>= 1) {
        p0 += __shfl_xor(p0, m);
        p1 += __shfl_xor(p1, m);
        p2 += __shfl_xor(p2, m);
      }
      if ((t & 31) == 0 && row < n) {
        out[row * 3 + 0] = p0;
        out[row * 3 + 1] = p1;
        out[row * 3 + 2] = p2;
      }
    }
  } else {
    #pragma unroll
    for (int r = 0; r < 4; ++r) {
      int row = row0 + tr + r;
      if (row < n) {
        float4 a = acc[r];
        float d = dis[row];
        a.x = silu_f(a.x + bb.x) * d;
        a.y = silu_f(a.y + bb.y) * d;
        a.z = silu_f(a.z + bb.z) * d;
        a.w = silu_f(a.w + bb.w) * d;
        *reinterpret_cast<float4*>(out + (size_t)row * 128 + tc) = a;
      }
    }
  }
}

extern "C" void kernel_launch(void* const* d_in, const int* in_sizes, int n_in,
                              void* d_out, int out_size, void* d_ws, size_t ws_size,
                              hipStream_t stream) {
  const float* pos = (const float*)d_in[0];
  const int* e32 = (const int*)d_in[1];
  const float* W[5] = {(const float*)d_in[2], (const float*)d_in[4], (const float*)d_in[6],
                       (const float*)d_in[8], (const float*)d_in[10]};
  const float* B[5] = {(const float*)d_in[3], (const float*)d_in[5], (const float*)d_in[7],
                       (const float*)d_in[9], (const float*)d_in[11]};
  float* out = (float*)d_out;

  const int N = in_sizes[0] / 3;
  const int E = in_sizes[1] / 2;
  const int NBUCKET = (N + (1 << BUCKET_SHIFT) - 1) >> BUCKET_SHIFT;  // 391
  const int M = NBUCKET * NB_SPLIT;
  const int chunk = (E + NB_SPLIT - 1) / NB_SPLIT;

  char* base = (char*)d_ws;
  size_t off = 0;
  auto alloc = [&](size_t bytes) -> void* {
    void* p = base + off;
    off += (bytes + 255) & ~(size_t)255;
    return p;
  };
  float* dis   = (float*)alloc((size_t)N * 4);
  int* rowp    = (int*)alloc((size_t)(N + 1) * 4);
  int* bsum2   = (int*)alloc(128 * 4);
  int* flag    = (int*)alloc(256);
  int* cnt2    = (int*)alloc((size_t)M * 4);
  int* off2    = (int*)alloc((size_t)M * 4);
  int* col     = (int*)alloc((size_t)E * 4);
  float* y3    = (float*)alloc((size_t)N * 3 * 4);
  float* bufA  = (float*)alloc((size_t)N * 128 * 4);
  float* bufB  = (float*)alloc((size_t)N * 128 * 4);
  // epack/tmp only live during CSR build; alias the big activation buffers.
  int* epack = (int*)bufA;
  int* tmp   = (int*)bufB;

  const int nblk2 = (M + 1023) / 1024;   // 98

  // --- CSR build ---
  k_detect<<<1, 256, 0, stream>>>(e32, flag);
  k_prep<<<NB_SPLIT, 256, 0, stream>>>(e32, flag, epack, cnt2, E, NBUCKET, chunk);
  k_scan1<<<nblk2, 256, 0, stream>>>(cnt2, off2, bsum2, M);
  k_scan2<<<1, 64, 0, stream>>>(bsum2, nblk2);
  k_scanadd<<<(M + 255) / 256, 256, 0, stream>>>(off2, bsum2, M);
  k_split<<<NB_SPLIT, 256, 0, stream>>>(epack, off2, tmp, E, NBUCKET, chunk);
  k_csr<<<NBUCKET, 256, 0, stream>>>(tmp, off2, rowp, dis, col, E, NBUCKET, N);

  // --- layer 0: 3-dim aggregate (prescale fused) then 3->128 matmul ---
  k_agg3<1><<<(N + 255) / 256, 256, 0, stream>>>(pos, y3, rowp, col, dis, nullptr, N);
  k_mm0<<<(N * 32 + 255) / 256, 256, 0, stream>>>(y3, W[0], B[0], dis, bufA, N);

  // --- layers 1..2: aggregate (128) then 128x128 matmul + SiLU + dis ---
  const int mm_grid = (N + 63) / 64;
  for (int l = 1; l <= 2; ++l) {
    k_agg128<<<(N + 3) / 4, 256, 0, stream>>>(bufA, bufB, rowp, col, dis, N);
    k_mm_w<0><<<mm_grid, 512, 0, stream>>>(bufB, W[l], B[l], dis, bufA, nullptr, N);
  }

  // --- layer 3: aggregate, matmul fused with layer-4's 128->3 projection ---
  k_agg128<<<(N + 3) / 4, 256, 0, stream>>>(bufA, bufB, rowp, col, dis, N);
  k_mm_w<1><<<mm_grid, 512, 0, stream>>>(bufB, W[3], B[3], dis, y3, W[4], N);

  // --- layer 4: 3-dim aggregate + bias ---
  k_agg3<0><<<(N + 255) / 256, 256, 0, stream>>>(y3, out, rowp, col, dis, B[4], N);

  (void)n_in; (void)out_size; (void)ws_size;
}